// Round 7
// baseline (225.611 us; speedup 1.0000x reference)
//
#include <hip/hip_runtime.h>

// 2-layer fused LSTM + linear head.  B=8192, T=128, D=32, H=64, gates=256.
// R7: TWO-STREAM SOFTWARE PIPELINE.  BT=32 (two 16-batch streams A,B per
// block), 512 thr / 8 waves, grid 256 (1 block/CU).  Each t-step has two
// windows separated by barriers:
//   W1(t): read+MFMA stream A (L0[t], L1[t-1])  ||  elem+write stream B
//          (finish B{L0[t-1], L1[t-2]} accs from W2(t-1))
//   W2(t): read+MFMA stream B                   ||  elem+write stream A
// So the pure-VALU elem burst of one stream fills the LDS/MFMA latency
// window of the other -> VALU never starves (R4-R6 lost ~40% to post-
// barrier quiet windows).  Weights shared by both streams.
// Wave wv owns h in [8wv,8wv+8) as 2 gate-interleaved row-tiles (R4 layout):
//   D element r of lane (bl,kg) = gate r of h = hbase+kg.
// log2e folded into weights; merged-rcp gate math = 7 trans/element.

#define TT  128
#define DIN 32
#define L2E 1.44269504088896340736f

typedef _Float16 h8 __attribute__((ext_vector_type(8)));
typedef __fp16   p2 __attribute__((ext_vector_type(2)));
typedef float    f4 __attribute__((ext_vector_type(4)));

#define MFMA(A, B, C) __builtin_amdgcn_mfma_f32_16x16x32_f16((A), (B), (C), 0, 0, 0)

__device__ __forceinline__ h8 cvt8s(const float* p, float s) {
    float4 a = *(const float4*)p;
    float4 b = *(const float4*)(p + 4);
    union { h8 v; p2 q[4]; } u;
    u.q[0] = __builtin_amdgcn_cvt_pkrtz(a.x * s, a.y * s);
    u.q[1] = __builtin_amdgcn_cvt_pkrtz(a.z * s, a.w * s);
    u.q[2] = __builtin_amdgcn_cvt_pkrtz(b.x * s, b.y * s);
    u.q[3] = __builtin_amdgcn_cvt_pkrtz(b.z * s, b.w * s);
    return u.v;
}

__device__ __forceinline__ h8 pack8(const float4& a, const float4& b) {
    union { h8 v; p2 q[4]; } u;
    u.q[0] = __builtin_amdgcn_cvt_pkrtz(a.x, a.y);
    u.q[1] = __builtin_amdgcn_cvt_pkrtz(a.z, a.w);
    u.q[2] = __builtin_amdgcn_cvt_pkrtz(b.x, b.y);
    u.q[3] = __builtin_amdgcn_cvt_pkrtz(b.z, b.w);
    return u.v;
}

// acc = {yi', yf', yg'(2x-scaled), yo'} (log2e pre-folded); updates c, returns h.
__device__ __forceinline__ float elem(const f4& acc, float& c) {
    float Ei = __builtin_amdgcn_exp2f(-acc[0]);
    float Ef = __builtin_amdgcn_exp2f(-acc[1]);
    float Eg = __builtin_amdgcn_exp2f(-acc[2]);
    float Eo = __builtin_amdgcn_exp2f(-acc[3]);
    float a = 1.f + Ei, b = 1.f + Eg, d = 1.f + Ef;
    float P = a * b;
    float N = c * P + (1.f - Eg) * d;
    c = N * __builtin_amdgcn_rcpf(P * d);
    float Ec = __builtin_amdgcn_exp2f(-2.f * L2E * c);
    return (1.f - Ec) * __builtin_amdgcn_rcpf((1.f + Ec) * (1.f + Eo));
}

__global__ __launch_bounds__(512, 2)
void lstm2_fused(const float* __restrict__ x,
                 const float* __restrict__ wih0, const float* __restrict__ whh0,
                 const float* __restrict__ bih0, const float* __restrict__ bhh0,
                 const float* __restrict__ wih1, const float* __restrict__ whh1,
                 const float* __restrict__ bih1, const float* __restrict__ bhh1,
                 const float* __restrict__ fcw,  const float* __restrict__ fcb,
                 float* __restrict__ out)
{
    const int tid  = threadIdx.x;
    const int lane = tid & 63;
    const int wv   = tid >> 6;      // 0..7 -> h block 8*wv
    const int bl   = lane & 15;
    const int kg   = lane >> 4;

    // [stream][layer][parity][b*64+h] f16, XOR-swizzled; 2048 B per buffer
    __shared__ alignas(16) unsigned short hb[2][2][2][16 * 64];   // 16 KB
    __shared__ float wpart[2][8][16];                             // 1 KB

    for (int i = tid; i < (int)(sizeof(hb) / 4); i += 512) ((int*)hb)[i] = 0;

    // ---- weights: gate-interleaved row tiles, log2e folded (shared A/B) ----
    h8 W0[2][3], W1[2][4];
    f4 b0v[2], b1v[2];
    #pragma unroll
    for (int k = 0; k < 2; ++k) {
        const int hbse = 8 * wv + 4 * k;
        const int gam  = bl & 3;
        const int g    = 64 * gam + hbse + (bl >> 2);
        const float sc = (gam == 2) ? 2.f * L2E : L2E;
        W0[k][0] = cvt8s(wih0 + g * 32 + 8 * kg, sc);
        W0[k][1] = cvt8s(whh0 + g * 64 + 8 * kg, sc);
        W0[k][2] = cvt8s(whh0 + g * 64 + 32 + 8 * kg, sc);
        W1[k][0] = cvt8s(wih1 + g * 64 + 8 * kg, sc);
        W1[k][1] = cvt8s(wih1 + g * 64 + 32 + 8 * kg, sc);
        W1[k][2] = cvt8s(whh1 + g * 64 + 8 * kg, sc);
        W1[k][3] = cvt8s(whh1 + g * 64 + 32 + 8 * kg, sc);
        #pragma unroll
        for (int r = 0; r < 4; ++r) {
            const int gr = 64 * r + hbse + kg;
            const float scr = (r == 2) ? 2.f * L2E : L2E;
            b0v[k][r] = (bih0[gr] + bhh0[gr]) * scr;
            b1v[k][r] = (bih1[gr] + bhh1[gr]) * scr;
        }
    }

    const int bbase = blockIdx.x * 32;
    const float* xpA = x + (size_t)(bbase + bl) * (TT * DIN) + 8 * kg;
    const float* xpB = xpA + 16 * (TT * DIN);

    float c0A[2] = {0.f, 0.f}, c1A[2] = {0.f, 0.f};
    float c0B[2] = {0.f, 0.f}, c1B[2] = {0.f, 0.f};
    f4 a0A[2], a1A[2], a0B[2], a1B[2];
    float h1fA[2], h1fB[2];

    const int swz = (bl & 7) << 4;
    char* lb = (char*)hb;
    const int rowoff = bl * 128;
    const int rd0  = rowoff + ((16 * kg) ^ swz);
    const int rd1  = rowoff + ((64 + 16 * kg) ^ swz);
    const int wro0 = rowoff + ((16 * wv + 2 * kg) ^ swz);      // h = 8wv+kg
    const int wro1 = rowoff + ((16 * wv + 8 + 2 * kg) ^ swz);  // h = 8wv+4+kg

    __syncthreads();   // LDS zero visible

    h8 xcurA = pack8(*(const float4*)xpA, *(const float4*)(xpA + 4));
    h8 xcurB = pack8(*(const float4*)xpB, *(const float4*)(xpB + 4));

    // LDS region bases: stream*8192 + layer*4096 + parity*2048
    for (int t = 0; t < TT; ++t) {
        const int p_t   = t & 1;
        const int p_tm1 = (t - 1) & 1;   // t=0 -> 1 (zeroed buffer)

        // ================= W1(t): compute A(t) || finish B =================
        {
            const int tn = (t + 1 < TT) ? t + 1 : TT - 1;
            float4 xa = *(const float4*)(xpA + tn * DIN);
            float4 xb = *(const float4*)(xpA + tn * DIN + 4);

            const char* rA0 = lb + 0 * 8192 + 0 * 4096 + p_tm1 * 2048;  // h0_A[t-1]
            h8 hr0 = *(const h8*)(rA0 + rd0);
            h8 hr1 = *(const h8*)(rA0 + rd1);
            #pragma unroll
            for (int k = 0; k < 2; ++k) {
                f4 acc = b0v[k];
                acc = MFMA(W0[k][1], hr0, acc);
                acc = MFMA(W0[k][2], hr1, acc);
                acc = MFMA(W0[k][0], xcurA, acc);
                a0A[k] = acc;
            }
            if (t >= 1) {
                const char* rA1 = lb + 0 * 8192 + 1 * 4096 + p_t * 2048; // h1_A[t-2]
                h8 g1a = *(const h8*)(rA1 + rd0);
                h8 g1b = *(const h8*)(rA1 + rd1);
                #pragma unroll
                for (int k = 0; k < 2; ++k) {
                    f4 acc = b1v[k];
                    acc = MFMA(W1[k][0], hr0, acc);
                    acc = MFMA(W1[k][1], hr1, acc);
                    acc = MFMA(W1[k][2], g1a, acc);
                    acc = MFMA(W1[k][3], g1b, acc);
                    a1A[k] = acc;
                }
            }
            if (t >= 1) {   // finish B{L0[t-1]} -> h0_B[t-1] parity p_tm1
                char* D = lb + 1 * 8192 + 0 * 4096 + p_tm1 * 2048;
                #pragma unroll
                for (int k = 0; k < 2; ++k) {
                    float h = elem(a0B[k], c0B[k]);
                    *(_Float16*)(D + (k ? wro1 : wro0)) = (_Float16)h;
                }
            }
            if (t >= 2) {   // finish B{L1[t-2]} -> h1_B[t-2] parity p_t
                char* D = lb + 1 * 8192 + 1 * 4096 + p_t * 2048;
                #pragma unroll
                for (int k = 0; k < 2; ++k) {
                    float h = elem(a1B[k], c1B[k]);
                    *(_Float16*)(D + (k ? wro1 : wro0)) = (_Float16)h;
                }
            }
            xcurA = pack8(xa, xb);
            __syncthreads();
        }

        // ================= W2(t): compute B(t) || finish A =================
        {
            const int tn = (t + 1 < TT) ? t + 1 : TT - 1;
            float4 xa = *(const float4*)(xpB + tn * DIN);
            float4 xb = *(const float4*)(xpB + tn * DIN + 4);

            const char* rB0 = lb + 1 * 8192 + 0 * 4096 + p_tm1 * 2048;  // h0_B[t-1]
            h8 hr0 = *(const h8*)(rB0 + rd0);
            h8 hr1 = *(const h8*)(rB0 + rd1);
            #pragma unroll
            for (int k = 0; k < 2; ++k) {
                f4 acc = b0v[k];
                acc = MFMA(W0[k][1], hr0, acc);
                acc = MFMA(W0[k][2], hr1, acc);
                acc = MFMA(W0[k][0], xcurB, acc);
                a0B[k] = acc;
            }
            if (t >= 1) {
                const char* rB1 = lb + 1 * 8192 + 1 * 4096 + p_t * 2048; // h1_B[t-2]
                h8 g1a = *(const h8*)(rB1 + rd0);
                h8 g1b = *(const h8*)(rB1 + rd1);
                #pragma unroll
                for (int k = 0; k < 2; ++k) {
                    f4 acc = b1v[k];
                    acc = MFMA(W1[k][0], hr0, acc);
                    acc = MFMA(W1[k][1], hr1, acc);
                    acc = MFMA(W1[k][2], g1a, acc);
                    acc = MFMA(W1[k][3], g1b, acc);
                    a1B[k] = acc;
                }
            }
            {   // finish A{L0[t]} -> h0_A[t] parity p_t
                char* D = lb + 0 * 8192 + 0 * 4096 + p_t * 2048;
                #pragma unroll
                for (int k = 0; k < 2; ++k) {
                    float h = elem(a0A[k], c0A[k]);
                    *(_Float16*)(D + (k ? wro1 : wro0)) = (_Float16)h;
                }
            }
            if (t >= 1) {   // finish A{L1[t-1]} -> h1_A[t-1] parity p_tm1
                char* D = lb + 0 * 8192 + 1 * 4096 + p_tm1 * 2048;
                #pragma unroll
                for (int k = 0; k < 2; ++k) {
                    float h = elem(a1A[k], c1A[k]);
                    *(_Float16*)(D + (k ? wro1 : wro0)) = (_Float16)h;
                }
            }
            xcurB = pack8(xa, xb);
            __syncthreads();
        }
    }

    // ===== epilogue =====
    // pending: a1A needs L1[127]; a0B/a1B hold B{L0[127], L1[126]}; then B L1[127].
    // E1: compute A L1[127] || finish B{L0[127] -> p1, L1[126] -> p0}
    {
        const char* rA0 = lb + 0 * 8192 + 0 * 4096 + 1 * 2048;   // h0_A[127] (p1)
        h8 hr0 = *(const h8*)(rA0 + rd0);
        h8 hr1 = *(const h8*)(rA0 + rd1);
        const char* rA1 = lb + 0 * 8192 + 1 * 4096 + 0 * 2048;   // h1_A[126] (p0)
        h8 g1a = *(const h8*)(rA1 + rd0);
        h8 g1b = *(const h8*)(rA1 + rd1);
        #pragma unroll
        for (int k = 0; k < 2; ++k) {
            f4 acc = b1v[k];
            acc = MFMA(W1[k][0], hr0, acc);
            acc = MFMA(W1[k][1], hr1, acc);
            acc = MFMA(W1[k][2], g1a, acc);
            acc = MFMA(W1[k][3], g1b, acc);
            a1A[k] = acc;
        }
        char* D0 = lb + 1 * 8192 + 0 * 4096 + 1 * 2048;
        char* D1 = lb + 1 * 8192 + 1 * 4096 + 0 * 2048;
        #pragma unroll
        for (int k = 0; k < 2; ++k) {
            float h0 = elem(a0B[k], c0B[k]);
            *(_Float16*)(D0 + (k ? wro1 : wro0)) = (_Float16)h0;
            float h1 = elem(a1B[k], c1B[k]);
            *(_Float16*)(D1 + (k ? wro1 : wro0)) = (_Float16)h1;
        }
        __syncthreads();
    }
    // E2: compute B L1[127] || finish A L1[127] (final, no store)
    {
        const char* rB0 = lb + 1 * 8192 + 0 * 4096 + 1 * 2048;   // h0_B[127] (p1)
        h8 hr0 = *(const h8*)(rB0 + rd0);
        h8 hr1 = *(const h8*)(rB0 + rd1);
        const char* rB1 = lb + 1 * 8192 + 1 * 4096 + 0 * 2048;   // h1_B[126] (p0)
        h8 g1a = *(const h8*)(rB1 + rd0);
        h8 g1b = *(const h8*)(rB1 + rd1);
        #pragma unroll
        for (int k = 0; k < 2; ++k) {
            f4 acc = b1v[k];
            acc = MFMA(W1[k][0], hr0, acc);
            acc = MFMA(W1[k][1], hr1, acc);
            acc = MFMA(W1[k][2], g1a, acc);
            acc = MFMA(W1[k][3], g1b, acc);
            a1B[k] = acc;
        }
        #pragma unroll
        for (int k = 0; k < 2; ++k) h1fA[k] = elem(a1A[k], c1A[k]);
    }
    // E3: finish B L1[127] (final)
    #pragma unroll
    for (int k = 0; k < 2; ++k) h1fB[k] = elem(a1B[k], c1B[k]);

    // ---- head: out[b] = h1 . fc_w + fc_b ----
    const float fw0 = fcw[8 * wv + kg];
    const float fw1 = fcw[8 * wv + 4 + kg];
    float pA = h1fA[0] * fw0 + h1fA[1] * fw1;
    float pB = h1fB[0] * fw0 + h1fB[1] * fw1;
    pA += __shfl_xor(pA, 16, 64);
    pA += __shfl_xor(pA, 32, 64);
    pB += __shfl_xor(pB, 16, 64);
    pB += __shfl_xor(pB, 32, 64);
    if (lane < 16) { wpart[0][wv][lane] = pA; wpart[1][wv][lane] = pB; }
    __syncthreads();
    if (tid < 32) {
        const int s = tid >> 4, b = tid & 15;
        float sum = fcb[0];
        #pragma unroll
        for (int w = 0; w < 8; ++w) sum += wpart[s][w][b];
        out[bbase + s * 16 + b] = sum;
    }
}

extern "C" void kernel_launch(void* const* d_in, const int* in_sizes, int n_in,
                              void* d_out, int out_size, void* d_ws, size_t ws_size,
                              hipStream_t stream) {
    (void)in_sizes; (void)n_in; (void)d_ws; (void)ws_size; (void)out_size;
    lstm2_fused<<<dim3(8192 / 32), dim3(512), 0, stream>>>(
        (const float*)d_in[0],
        (const float*)d_in[1], (const float*)d_in[2],
        (const float*)d_in[3], (const float*)d_in[4],
        (const float*)d_in[5], (const float*)d_in[6],
        (const float*)d_in[7], (const float*)d_in[8],
        (const float*)d_in[9], (const float*)d_in[10],
        (float*)d_out);
}